// Round 2
// baseline (638.547 us; speedup 1.0000x reference)
//
#include <hip/hip_runtime.h>

#define D 4096
#define CSTRIDE 2016   // codes per row: 16*(2+4+8+16+32+64); offsets {0,32,96,224,480,992}

typedef unsigned short u16;
typedef __bf16 bf16x8 __attribute__((ext_vector_type(8)));
typedef u16    u16x8  __attribute__((ext_vector_type(8)));
typedef u16    u16x4v __attribute__((ext_vector_type(4)));
typedef float  f32x4  __attribute__((ext_vector_type(4)));

__device__ __forceinline__ u16 f2bf(float f) {   // RNE float->bf16 (finite inputs)
    unsigned u = __float_as_uint(f);
    u += 0x7fffu + ((u >> 16) & 1u);
    return (u16)(u >> 16);
}

// -------------------- Kernel 0: weight prep (bf16 transposes) ---------------
// usT[i][(j*16+r)*s + k] = us[i][j][k][r]          (6 * 65536 elements)
// WT[b][n*160 + k]: k<64 -> ds[b][k][n]; k=64+i*16+r -> vs[i][sib][r][loc*64+n]
__global__ __launch_bounds__(256) void hodlr_prep(
    const float* __restrict__ us0, const float* __restrict__ us1,
    const float* __restrict__ us2, const float* __restrict__ us3,
    const float* __restrict__ us4, const float* __restrict__ us5,
    const float* __restrict__ vs0, const float* __restrict__ vs1,
    const float* __restrict__ vs2, const float* __restrict__ vs3,
    const float* __restrict__ vs4, const float* __restrict__ vs5,
    const float* __restrict__ dsm,
    u16* __restrict__ usT, u16* __restrict__ WT)
{
    const float* usp[6] = {us0, us1, us2, us3, us4, us5};
    const float* vsp[6] = {vs0, vs1, vs2, vs3, vs4, vs5};
    const int idx = blockIdx.x * 256 + threadIdx.x;
    if (idx < 6 * 65536) {
        const int i = idx >> 16, rem = idx & 65535;
        const int lg = 11 - i, s = 2048 >> i;
        const int jr = rem >> lg, k = rem & (s - 1);
        const int j = jr >> 4, r = jr & 15;
        usT[idx] = f2bf(usp[i][(size_t)(j * s + k) * 16 + r]);
    } else if (idx < 6 * 65536 + 64 * 10240) {
        const int w = idx - 6 * 65536;
        const int b = w / 10240, rem = w - b * 10240;
        const int n = rem / 160, k = rem - n * 160;
        float val;
        if (k < 64) {
            val = dsm[b * 4096 + k * 64 + n];
        } else {
            const int i = (k - 64) >> 4, r = (k - 64) & 15;
            const int s = 2048 >> i;
            const int sib = (b >> (5 - i)) ^ 1;
            const int loc = b & ((1 << (5 - i)) - 1);
            val = vsp[i][(size_t)sib * 16 * s + r * s + loc * 64 + n];
        }
        WT[w] = f2bf(val);
    }
}

// -------------------- Kernel 1: rank-16 codes via MFMA ----------------------
// v3: K split 8 ways (512-col segments) -> grid (T/64, 8) = 2048 blocks =
// 8 blocks/CU = 32 waves/CU (round-1 showed the old (T/64,2) grid was
// occupancy-capped at 2 waves/SIMD and ~96% stalled; intra-wave pipelining
// was neutral, so the cure is TLP, not scheduling).
// Layers 2-5 (s<=512) complete within a segment -> bf16 codes as before.
// Layers 0-1 (s=2048/1024) straddle segments -> fp32 partials, reduced by
// hodlr_reduce into the layer-0/1 code slots (deterministic, no atomics).
__global__ __launch_bounds__(256, 8) void hodlr_codes(
    const float* __restrict__ x, const u16* __restrict__ usT,
    u16* __restrict__ codes, float* __restrict__ part)
{
    __shared__ __align__(16) u16 uss[6 * 16 * 72];   // [layer][rank][72], 13.8 KB

    const int tid = threadIdx.x, lane = tid & 63, wv = tid >> 6;
    const int m = lane & 15, quad = lane >> 4;
    const int t0 = blockIdx.x * 64;
    const int seg = blockIdx.y;                 // 0..7
    const int kbase = seg * 512;
    const float* xrow = x + (size_t)(t0 + wv * 16 + m) * D;

    f32x4 acc[6];
    #pragma unroll
    for (int i = 0; i < 6; ++i) acc[i] = (f32x4){0.f, 0.f, 0.f, 0.f};

    for (int c = 0; c < 8; ++c) {
        const int kb = kbase + c * 64;
        __syncthreads();   // previous chunk's B-frag readers done with uss
        // A: 64 cols of this lane's row (k = quad*8 + e within each 32-step)
        const float4 xv0 = *(const float4*)(xrow + kb + quad * 8);
        const float4 xv1 = *(const float4*)(xrow + kb + quad * 8 + 4);
        const float4 xv2 = *(const float4*)(xrow + kb + 32 + quad * 8);
        const float4 xv3 = *(const float4*)(xrow + kb + 32 + quad * 8 + 4);
        // stage usT slices: 6 layers x 16 ranks x 64 k (bf16), 3 x b128/thread
        #pragma unroll
        for (int p = 0; p < 3; ++p) {
            const int u = tid + p * 256;            // 0..767
            const int i = u >> 7, rem = u & 127, r = rem >> 3, sg = rem & 7;
            const int lg = 11 - i;
            const int j = kb >> lg;
            const int koff = kb & ((2048 >> i) - 1);
            const size_t src = ((size_t)i << 16) + ((size_t)((j << 4) + r) << lg)
                             + koff + (sg << 3);
            *(float4*)&uss[(i * 16 + r) * 72 + (sg << 3)] =
                *(const float4*)(usT + src);
        }
        __syncthreads();

        union { u16x8 u; bf16x8 v; } a0, a1;
        a0.u[0] = f2bf(xv0.x); a0.u[1] = f2bf(xv0.y); a0.u[2] = f2bf(xv0.z); a0.u[3] = f2bf(xv0.w);
        a0.u[4] = f2bf(xv1.x); a0.u[5] = f2bf(xv1.y); a0.u[6] = f2bf(xv1.z); a0.u[7] = f2bf(xv1.w);
        a1.u[0] = f2bf(xv2.x); a1.u[1] = f2bf(xv2.y); a1.u[2] = f2bf(xv2.z); a1.u[3] = f2bf(xv2.w);
        a1.u[4] = f2bf(xv3.x); a1.u[5] = f2bf(xv3.y); a1.u[6] = f2bf(xv3.z); a1.u[7] = f2bf(xv3.w);

        #pragma unroll
        for (int i = 0; i < 6; ++i) {
            const u16* bp = &uss[(i * 16 + m) * 72 + quad * 8];
            const bf16x8 b0 = *(const bf16x8*)bp;
            const bf16x8 b1 = *(const bf16x8*)(bp + 32);
            acc[i] = __builtin_amdgcn_mfma_f32_16x16x32_bf16(a0.v, b0, acc[i], 0, 0, 0);
            acc[i] = __builtin_amdgcn_mfma_f32_16x16x32_bf16(a1.v, b1, acc[i], 0, 0, 0);
        }
        // flush finished blocks for layers 2-5 only (s <= 512 completes here)
        // C layout: col=lane&15, row=quad*4+reg
        #pragma unroll
        for (int i = 2; i < 6; ++i) {
            const int s = 2048 >> i;
            if (((kb + 64) & (s - 1)) == 0) {
                const int j = kb >> (11 - i);
                const int offt = 16 * ((2 << i) - 2);
                u16* cp = codes + (size_t)(t0 + wv * 16 + quad * 4) * CSTRIDE
                        + offt + j * 16 + m;
                cp[0 * CSTRIDE] = f2bf(acc[i][0]);
                cp[1 * CSTRIDE] = f2bf(acc[i][1]);
                cp[2 * CSTRIDE] = f2bf(acc[i][2]);
                cp[3 * CSTRIDE] = f2bf(acc[i][3]);
                acc[i] = (f32x4){0.f, 0.f, 0.f, 0.f};
            }
        }
    }

    // epilogue: layer 0/1 partial sums over this 512-col segment, fp32.
    // part[(row*8 + seg)*32 + l*16 + r]
    const int prow = t0 + wv * 16 + quad * 4;
    float* pp = part + ((size_t)prow * 8 + seg) * 32 + m;
    #pragma unroll
    for (int v = 0; v < 4; ++v) {
        pp[(size_t)v * 256]      = acc[0][v];
        pp[(size_t)v * 256 + 16] = acc[1][v];
    }
}

// -------------------- Kernel 1b: reduce layer-0/1 partials to bf16 codes ----
// code0[row][j][r] = sum_{q=0..3} part[(row*8 + j*4+q)*32 + r]       (slot j*16+r)
// code1[row][j][r] = sum_{q=0..1} part[(row*8 + j*2+q)*32 + 16 + r]  (slot 32+j*16+r)
__global__ __launch_bounds__(256) void hodlr_reduce(
    const float* __restrict__ part, u16* __restrict__ codes)
{
    const int idx = blockIdx.x * 256 + threadIdx.x;   // T*96
    const int row = idx / 96, rem = idx - row * 96;
    float s;
    int off;
    if (rem < 32) {
        const int j = rem >> 4, r = rem & 15;
        const float* p = part + ((size_t)row * 8 + j * 4) * 32 + r;
        s = (p[0] + p[32]) + (p[64] + p[96]);
        off = j * 16 + r;
    } else {
        const int rm = rem - 32, j = rm >> 4, r = rm & 15;
        const float* p = part + ((size_t)row * 8 + j * 2) * 32 + 16 + r;
        s = p[0] + p[32];
        off = 32 + j * 16 + r;
    }
    codes[(size_t)row * CSTRIDE + off] = f2bf(s);
}

// -------------------- Kernel 2: output GEMMs via MFMA -----------------------
// Grid (64, T/64). A(64x160) = [x_chunk bf16 | sibling codes], B = WT[b],
// 5 K-steps x 4 n-tiles; epilogue repacks C through LDS for float4 stores.
__global__ __launch_bounds__(256) void hodlr_out(
    const float* __restrict__ x, const u16* __restrict__ codes,
    const u16* __restrict__ WT, const float* __restrict__ bias,
    float* __restrict__ out)
{
    __shared__ __align__(16) u16 As[64 * 168];   // [row][k], stride 168 bf16
    __shared__ __align__(16) u16 Ws[64 * 168];   // [n][k]

    const int tid = threadIdx.x, lane = tid & 63, wv = tid >> 6;
    const int m = lane & 15, quad = lane >> 4;
    const int bch = blockIdx.x, t0 = blockIdx.y * 64;

    // ---- stage A: x chunk (64 rows x 64 cols), fp32->bf16
    #pragma unroll
    for (int p = 0; p < 4; ++p) {
        const int idx = tid + p * 256;            // 0..1023
        const int row = idx >> 4, c4 = idx & 15;
        const float4 xv = *(const float4*)(x + (size_t)(t0 + row) * D + bch * 64 + c4 * 4);
        u16x4v pk; pk[0] = f2bf(xv.x); pk[1] = f2bf(xv.y); pk[2] = f2bf(xv.z); pk[3] = f2bf(xv.w);
        *(u16x4v*)&As[row * 168 + c4 * 4] = pk;
    }
    // ---- stage A: sibling codes (64 rows x 6 layers x 16), raw bf16 copy
    #pragma unroll
    for (int p = 0; p < 3; ++p) {
        const int u = tid + p * 256;              // 0..767
        const int row = u / 12, rem = u - row * 12, i = rem >> 1, h = rem & 1;
        const int offt = 16 * ((2 << i) - 2);
        const int sib = (bch >> (5 - i)) ^ 1;
        *(float4*)&As[row * 168 + 64 + i * 16 + h * 8] =
            *(const float4*)(codes + (size_t)(t0 + row) * CSTRIDE + offt + sib * 16 + h * 8);
    }
    // ---- stage B: WT[b] (64 n x 160 k bf16, contiguous)
    #pragma unroll
    for (int p = 0; p < 5; ++p) {
        const int u = tid + p * 256;              // 0..1279
        const int n = u / 20, sg = u - n * 20;
        *(float4*)&Ws[n * 168 + sg * 8] =
            *(const float4*)(WT + (size_t)bch * 10240 + (size_t)u * 8);
    }
    __syncthreads();

    f32x4 acc[4];
    #pragma unroll
    for (int nt = 0; nt < 4; ++nt) acc[nt] = (f32x4){0.f, 0.f, 0.f, 0.f};

    #pragma unroll
    for (int s = 0; s < 5; ++s) {
        const bf16x8 a = *(const bf16x8*)&As[(wv * 16 + m) * 168 + s * 32 + quad * 8];
        #pragma unroll
        for (int nt = 0; nt < 4; ++nt) {
            const bf16x8 b = *(const bf16x8*)&Ws[(nt * 16 + m) * 168 + s * 32 + quad * 8];
            acc[nt] = __builtin_amdgcn_mfma_f32_16x16x32_bf16(a, b, acc[nt], 0, 0, 0);
        }
    }
    __syncthreads();   // all waves done reading As/Ws

    // ---- epilogue: repack C via LDS (reuse As as fp32 64x68), +bias, float4 out
    float* Of = (float*)As;
    #pragma unroll
    for (int nt = 0; nt < 4; ++nt)
        #pragma unroll
        for (int v = 0; v < 4; ++v)
            Of[(wv * 16 + quad * 4 + v) * 68 + nt * 16 + m] = acc[nt][v];
    __syncthreads();

    #pragma unroll
    for (int p = 0; p < 4; ++p) {
        const int u = tid + p * 256;              // 0..1023
        const int row = u >> 4, sg = u & 15;      // sg: float4 within 64 cols
        float4 val = *(const float4*)&Of[row * 68 + sg * 4];
        const float4 bv = *(const float4*)(bias + bch * 64 + sg * 4);
        val.x += bv.x; val.y += bv.y; val.z += bv.z; val.w += bv.w;
        *(float4*)(out + (size_t)(t0 + row) * D + bch * 64 + sg * 4) = val;
    }
}

// -------------------- launch ----------------------------------------------
extern "C" void kernel_launch(void* const* d_in, const int* in_sizes, int n_in,
                              void* d_out, int out_size, void* d_ws, size_t ws_size,
                              hipStream_t stream)
{
    const float* x   = (const float*)d_in[0];
    const float* us0 = (const float*)d_in[1];
    const float* vs0 = (const float*)d_in[2];
    const float* us1 = (const float*)d_in[3];
    const float* vs1 = (const float*)d_in[4];
    const float* us2 = (const float*)d_in[5];
    const float* vs2 = (const float*)d_in[6];
    const float* us3 = (const float*)d_in[7];
    const float* vs3 = (const float*)d_in[8];
    const float* us4 = (const float*)d_in[9];
    const float* vs4 = (const float*)d_in[10];
    const float* us5 = (const float*)d_in[11];
    const float* vs5 = (const float*)d_in[12];
    const float* dsm = (const float*)d_in[13];
    const float* bias= (const float*)d_in[14];
    float* out = (float*)d_out;

    const int T = in_sizes[0] / D;               // 16384 rows

    // ws layout: codes (u16, T*2016) | usT (u16) | WT (u16) | part (f32, T*8*32)
    u16* codes = (u16*)d_ws;                     // T*2016
    u16* usT   = codes + (size_t)T * CSTRIDE;    // 6*65536
    u16* WTp   = usT + 6 * 65536;                // 64*10240
    float* part = (float*)(WTp + 64 * 10240);    // T*256 fp32 (16B-aligned)

    hipLaunchKernelGGL(hodlr_prep, dim3((6 * 65536 + 64 * 10240) / 256), dim3(256), 0, stream,
                       us0, us1, us2, us3, us4, us5,
                       vs0, vs1, vs2, vs3, vs4, vs5, dsm, usT, WTp);
    hipLaunchKernelGGL(hodlr_codes, dim3(T / 64, 8), dim3(256), 0, stream,
                       x, usT, codes, part);
    hipLaunchKernelGGL(hodlr_reduce, dim3(T * 96 / 256), dim3(256), 0, stream,
                       part, codes);
    hipLaunchKernelGGL(hodlr_out, dim3(64, T / 64), dim3(256), 0, stream,
                       x, codes, WTp, bias, out);
}

// Round 3
// 629.807 us; speedup vs baseline: 1.0139x; 1.0139x over previous
//
#include <hip/hip_runtime.h>

#define D 4096
#define CSTRIDE 2016   // codes per row: 16*(2+4+8+16+32+64); offsets {0,32,96,224,480,992}

typedef unsigned short u16;
typedef __bf16 bf16x8 __attribute__((ext_vector_type(8)));
typedef u16    u16x8  __attribute__((ext_vector_type(8)));
typedef u16    u16x4v __attribute__((ext_vector_type(4)));
typedef float  f32x4  __attribute__((ext_vector_type(4)));

__device__ __forceinline__ u16 f2bf(float f) {   // RNE float->bf16 (finite inputs)
    unsigned u = __float_as_uint(f);
    u += 0x7fffu + ((u >> 16) & 1u);
    return (u16)(u >> 16);
}

// -------------------- Kernel 0: weight prep (bf16 transposes) ---------------
// usT[i][(j*16+r)*s + k] = us[i][j][k][r]          (6 * 65536 elements)
// WT[b][n*160 + k]: k<64 -> ds[b][k][n]; k=64+i*16+r -> vs[i][sib][r][loc*64+n]
__global__ __launch_bounds__(256) void hodlr_prep(
    const float* __restrict__ us0, const float* __restrict__ us1,
    const float* __restrict__ us2, const float* __restrict__ us3,
    const float* __restrict__ us4, const float* __restrict__ us5,
    const float* __restrict__ vs0, const float* __restrict__ vs1,
    const float* __restrict__ vs2, const float* __restrict__ vs3,
    const float* __restrict__ vs4, const float* __restrict__ vs5,
    const float* __restrict__ dsm,
    u16* __restrict__ usT, u16* __restrict__ WT)
{
    const float* usp[6] = {us0, us1, us2, us3, us4, us5};
    const float* vsp[6] = {vs0, vs1, vs2, vs3, vs4, vs5};
    const int idx = blockIdx.x * 256 + threadIdx.x;
    if (idx < 6 * 65536) {
        const int i = idx >> 16, rem = idx & 65535;
        const int lg = 11 - i, s = 2048 >> i;
        const int jr = rem >> lg, k = rem & (s - 1);
        const int j = jr >> 4, r = jr & 15;
        usT[idx] = f2bf(usp[i][(size_t)(j * s + k) * 16 + r]);
    } else if (idx < 6 * 65536 + 64 * 10240) {
        const int w = idx - 6 * 65536;
        const int b = w / 10240, rem = w - b * 10240;
        const int n = rem / 160, k = rem - n * 160;
        float val;
        if (k < 64) {
            val = dsm[b * 4096 + k * 64 + n];
        } else {
            const int i = (k - 64) >> 4, r = (k - 64) & 15;
            const int s = 2048 >> i;
            const int sib = (b >> (5 - i)) ^ 1;
            const int loc = b & ((1 << (5 - i)) - 1);
            val = vsp[i][(size_t)sib * 16 * s + r * s + loc * 64 + n];
        }
        WT[w] = f2bf(val);
    }
}

// -------------------- Kernel 1: rank-16 codes via MFMA ----------------------
// v4: fully-coalesced x access. Rounds 1-2 proved the 166 us plateau is
// invariant to both pipelining and occupancy; the remaining suspect is the
// address/miss path — the old per-lane-row x loads touched 32 scattered
// cache lines per instruction. Now x is staged through LDS: each wave loads
// 4 rows x 256B contiguous runs (dense 16 lines/instr), converts fp32->bf16,
// writes xs[64][72] (stride-72 bank-safe like uss), and A-fragments come
// back as ds_read_b128. Grid/flush/partials unchanged from v3.
__global__ __launch_bounds__(256, 6) void hodlr_codes(
    const float* __restrict__ x, const u16* __restrict__ usT,
    u16* __restrict__ codes, float* __restrict__ part)
{
    __shared__ __align__(16) u16 uss[6 * 16 * 72];   // [layer][rank][72], 13.8 KB
    __shared__ __align__(16) u16 xs[64 * 72];        // bf16 x-tile, 9 KB

    const int tid = threadIdx.x, lane = tid & 63, wv = tid >> 6;
    const int m = lane & 15, quad = lane >> 4;
    const int t0 = blockIdx.x * 64;
    const int seg = blockIdx.y;                 // 0..7
    const int kbase = seg * 512;

    // coalesced x staging: thread covers rows srow+{0,16,32,48}, 4 cols at scol
    const int srow = tid >> 4, scol = (tid & 15) * 4;

    f32x4 acc[6];
    #pragma unroll
    for (int i = 0; i < 6; ++i) acc[i] = (f32x4){0.f, 0.f, 0.f, 0.f};

    for (int c = 0; c < 8; ++c) {
        const int kb = kbase + c * 64;
        __syncthreads();   // previous chunk's LDS readers done

        // ---- issue all global loads first (x coalesced, then usT)
        float4 xv[4];
        #pragma unroll
        for (int p = 0; p < 4; ++p)
            xv[p] = *(const float4*)(x + (size_t)(t0 + srow + p * 16) * D + kb + scol);

        float4 uv[3];
        int uOff[3];
        #pragma unroll
        for (int p = 0; p < 3; ++p) {
            const int u = tid + p * 256;            // 0..767
            const int i = u >> 7, rem = u & 127, r = rem >> 3, sg = rem & 7;
            const int lg = 11 - i;
            const int j = kb >> lg;
            const int koff = kb & ((2048 >> i) - 1);
            const size_t src = ((size_t)i << 16) + ((size_t)((j << 4) + r) << lg)
                             + koff + (sg << 3);
            uv[p] = *(const float4*)(usT + src);
            uOff[p] = (i * 16 + r) * 72 + (sg << 3);
        }

        // ---- commit to LDS: x (fp32->bf16) and usT slices
        #pragma unroll
        for (int p = 0; p < 4; ++p) {
            u16x4v pk;
            pk[0] = f2bf(xv[p].x); pk[1] = f2bf(xv[p].y);
            pk[2] = f2bf(xv[p].z); pk[3] = f2bf(xv[p].w);
            *(u16x4v*)&xs[(srow + p * 16) * 72 + scol] = pk;
        }
        #pragma unroll
        for (int p = 0; p < 3; ++p)
            *(float4*)&uss[uOff[p]] = uv[p];
        __syncthreads();

        // ---- A-fragments from LDS (stride-72: bank-safe, 2-way max)
        const u16* ap = &xs[(wv * 16 + m) * 72 + quad * 8];
        union { u16x8 u; bf16x8 v; } a0, a1;
        a0.u = *(const u16x8*)ap;
        a1.u = *(const u16x8*)(ap + 32);

        #pragma unroll
        for (int i = 0; i < 6; ++i) {
            const u16* bp = &uss[(i * 16 + m) * 72 + quad * 8];
            const bf16x8 b0 = *(const bf16x8*)bp;
            const bf16x8 b1 = *(const bf16x8*)(bp + 32);
            acc[i] = __builtin_amdgcn_mfma_f32_16x16x32_bf16(a0.v, b0, acc[i], 0, 0, 0);
            acc[i] = __builtin_amdgcn_mfma_f32_16x16x32_bf16(a1.v, b1, acc[i], 0, 0, 0);
        }
        // flush finished blocks for layers 2-5 only (s <= 512 completes here)
        // C layout: col=lane&15, row=quad*4+reg
        #pragma unroll
        for (int i = 2; i < 6; ++i) {
            const int s = 2048 >> i;
            if (((kb + 64) & (s - 1)) == 0) {
                const int j = kb >> (11 - i);
                const int offt = 16 * ((2 << i) - 2);
                u16* cp = codes + (size_t)(t0 + wv * 16 + quad * 4) * CSTRIDE
                        + offt + j * 16 + m;
                cp[0 * CSTRIDE] = f2bf(acc[i][0]);
                cp[1 * CSTRIDE] = f2bf(acc[i][1]);
                cp[2 * CSTRIDE] = f2bf(acc[i][2]);
                cp[3 * CSTRIDE] = f2bf(acc[i][3]);
                acc[i] = (f32x4){0.f, 0.f, 0.f, 0.f};
            }
        }
    }

    // epilogue: layer 0/1 partial sums over this 512-col segment, fp32.
    // part[(row*8 + seg)*32 + l*16 + r]
    const int prow = t0 + wv * 16 + quad * 4;
    float* pp = part + ((size_t)prow * 8 + seg) * 32 + m;
    #pragma unroll
    for (int v = 0; v < 4; ++v) {
        pp[(size_t)v * 256]      = acc[0][v];
        pp[(size_t)v * 256 + 16] = acc[1][v];
    }
}

// -------------------- Kernel 1b: reduce layer-0/1 partials to bf16 codes ----
// code0[row][j][r] = sum_{q=0..3} part[(row*8 + j*4+q)*32 + r]       (slot j*16+r)
// code1[row][j][r] = sum_{q=0..1} part[(row*8 + j*2+q)*32 + 16 + r]  (slot 32+j*16+r)
__global__ __launch_bounds__(256) void hodlr_reduce(
    const float* __restrict__ part, u16* __restrict__ codes)
{
    const int idx = blockIdx.x * 256 + threadIdx.x;   // T*96
    const int row = idx / 96, rem = idx - row * 96;
    float s;
    int off;
    if (rem < 32) {
        const int j = rem >> 4, r = rem & 15;
        const float* p = part + ((size_t)row * 8 + j * 4) * 32 + r;
        s = (p[0] + p[32]) + (p[64] + p[96]);
        off = j * 16 + r;
    } else {
        const int rm = rem - 32, j = rm >> 4, r = rm & 15;
        const float* p = part + ((size_t)row * 8 + j * 2) * 32 + 16 + r;
        s = p[0] + p[32];
        off = 32 + j * 16 + r;
    }
    codes[(size_t)row * CSTRIDE + off] = f2bf(s);
}

// -------------------- Kernel 2: output GEMMs via MFMA -----------------------
// Grid (64, T/64). A(64x160) = [x_chunk bf16 | sibling codes], B = WT[b],
// 5 K-steps x 4 n-tiles; epilogue repacks C through LDS for float4 stores.
__global__ __launch_bounds__(256) void hodlr_out(
    const float* __restrict__ x, const u16* __restrict__ codes,
    const u16* __restrict__ WT, const float* __restrict__ bias,
    float* __restrict__ out)
{
    __shared__ __align__(16) u16 As[64 * 168];   // [row][k], stride 168 bf16
    __shared__ __align__(16) u16 Ws[64 * 168];   // [n][k]

    const int tid = threadIdx.x, lane = tid & 63, wv = tid >> 6;
    const int m = lane & 15, quad = lane >> 4;
    const int bch = blockIdx.x, t0 = blockIdx.y * 64;

    // ---- stage A: x chunk (64 rows x 64 cols), fp32->bf16
    #pragma unroll
    for (int p = 0; p < 4; ++p) {
        const int idx = tid + p * 256;            // 0..1023
        const int row = idx >> 4, c4 = idx & 15;
        const float4 xv = *(const float4*)(x + (size_t)(t0 + row) * D + bch * 64 + c4 * 4);
        u16x4v pk; pk[0] = f2bf(xv.x); pk[1] = f2bf(xv.y); pk[2] = f2bf(xv.z); pk[3] = f2bf(xv.w);
        *(u16x4v*)&As[row * 168 + c4 * 4] = pk;
    }
    // ---- stage A: sibling codes (64 rows x 6 layers x 16), raw bf16 copy
    #pragma unroll
    for (int p = 0; p < 3; ++p) {
        const int u = tid + p * 256;              // 0..767
        const int row = u / 12, rem = u - row * 12, i = rem >> 1, h = rem & 1;
        const int offt = 16 * ((2 << i) - 2);
        const int sib = (bch >> (5 - i)) ^ 1;
        *(float4*)&As[row * 168 + 64 + i * 16 + h * 8] =
            *(const float4*)(codes + (size_t)(t0 + row) * CSTRIDE + offt + sib * 16 + h * 8);
    }
    // ---- stage B: WT[b] (64 n x 160 k bf16, contiguous)
    #pragma unroll
    for (int p = 0; p < 5; ++p) {
        const int u = tid + p * 256;              // 0..1279
        const int n = u / 20, sg = u - n * 20;
        *(float4*)&Ws[n * 168 + sg * 8] =
            *(const float4*)(WT + (size_t)bch * 10240 + (size_t)u * 8);
    }
    __syncthreads();

    f32x4 acc[4];
    #pragma unroll
    for (int nt = 0; nt < 4; ++nt) acc[nt] = (f32x4){0.f, 0.f, 0.f, 0.f};

    #pragma unroll
    for (int s = 0; s < 5; ++s) {
        const bf16x8 a = *(const bf16x8*)&As[(wv * 16 + m) * 168 + s * 32 + quad * 8];
        #pragma unroll
        for (int nt = 0; nt < 4; ++nt) {
            const bf16x8 b = *(const bf16x8*)&Ws[(nt * 16 + m) * 168 + s * 32 + quad * 8];
            acc[nt] = __builtin_amdgcn_mfma_f32_16x16x32_bf16(a, b, acc[nt], 0, 0, 0);
        }
    }
    __syncthreads();   // all waves done reading As/Ws

    // ---- epilogue: repack C via LDS (reuse As as fp32 64x68), +bias, float4 out
    float* Of = (float*)As;
    #pragma unroll
    for (int nt = 0; nt < 4; ++nt)
        #pragma unroll
        for (int v = 0; v < 4; ++v)
            Of[(wv * 16 + quad * 4 + v) * 68 + nt * 16 + m] = acc[nt][v];
    __syncthreads();

    #pragma unroll
    for (int p = 0; p < 4; ++p) {
        const int u = tid + p * 256;              // 0..1023
        const int row = u >> 4, sg = u & 15;      // sg: float4 within 64 cols
        float4 val = *(const float4*)&Of[row * 68 + sg * 4];
        const float4 bv = *(const float4*)(bias + bch * 64 + sg * 4);
        val.x += bv.x; val.y += bv.y; val.z += bv.z; val.w += bv.w;
        *(float4*)(out + (size_t)(t0 + row) * D + bch * 64 + sg * 4) = val;
    }
}

// -------------------- launch ----------------------------------------------
extern "C" void kernel_launch(void* const* d_in, const int* in_sizes, int n_in,
                              void* d_out, int out_size, void* d_ws, size_t ws_size,
                              hipStream_t stream)
{
    const float* x   = (const float*)d_in[0];
    const float* us0 = (const float*)d_in[1];
    const float* vs0 = (const float*)d_in[2];
    const float* us1 = (const float*)d_in[3];
    const float* vs1 = (const float*)d_in[4];
    const float* us2 = (const float*)d_in[5];
    const float* vs2 = (const float*)d_in[6];
    const float* us3 = (const float*)d_in[7];
    const float* vs3 = (const float*)d_in[8];
    const float* us4 = (const float*)d_in[9];
    const float* vs4 = (const float*)d_in[10];
    const float* us5 = (const float*)d_in[11];
    const float* vs5 = (const float*)d_in[12];
    const float* dsm = (const float*)d_in[13];
    const float* bias= (const float*)d_in[14];
    float* out = (float*)d_out;

    const int T = in_sizes[0] / D;               // 16384 rows

    // ws layout: codes (u16, T*2016) | usT (u16) | WT (u16) | part (f32, T*8*32)
    u16* codes = (u16*)d_ws;                     // T*2016
    u16* usT   = codes + (size_t)T * CSTRIDE;    // 6*65536
    u16* WTp   = usT + 6 * 65536;                // 64*10240
    float* part = (float*)(WTp + 64 * 10240);    // T*256 fp32 (16B-aligned)

    hipLaunchKernelGGL(hodlr_prep, dim3((6 * 65536 + 64 * 10240) / 256), dim3(256), 0, stream,
                       us0, us1, us2, us3, us4, us5,
                       vs0, vs1, vs2, vs3, vs4, vs5, dsm, usT, WTp);
    hipLaunchKernelGGL(hodlr_codes, dim3(T / 64, 8), dim3(256), 0, stream,
                       x, usT, codes, part);
    hipLaunchKernelGGL(hodlr_reduce, dim3(T * 96 / 256), dim3(256), 0, stream,
                       part, codes);
    hipLaunchKernelGGL(hodlr_out, dim3(64, T / 64), dim3(256), 0, stream,
                       x, codes, WTp, bias, out);
}